// Round 2
// baseline (270.025 us; speedup 1.0000x reference)
//
#include <hip/hip_runtime.h>

#define B_    16
#define Q_    300
#define S_    16
#define HID_  256
#define SSCALE 0.077f
// Only level 0 (H=W=100, start 0) and queries 0..2 matter:
// reference gathers emb[b, 0, ref_levels[b,q], s, c] with ref_levels in {0,1,2}.

// One block per sample point (b, qi in {0,1,2}, s). Computes the bilinear
// sample g[256], then h1 = tanh(g@w1+b1), off = h1@w2+b2, and stores
// SSCALE*tanh(off) into off_table[b*3+qi][s][4].
__global__ __launch_bounds__(256) void sample_mlp_kernel(
    const float* __restrict__ ref_polys,   // [B,Q,8]
    const float* __restrict__ memory,      // [B,13125,256]
    const float* __restrict__ w1,          // [256,256]
    const float* __restrict__ b1,          // [256]
    const float* __restrict__ w2,          // [256,4]
    const float* __restrict__ b2,          // [4]
    float* __restrict__ off_table)         // [B*3,16,4]
{
    const int blk = blockIdx.x;        // 0..767
    const int s   = blk & 15;
    const int bq  = blk >> 4;          // 0..47 = b*3+qi
    const int b   = bq / 3;
    const int qi  = bq - b * 3;
    const int tid = threadIdx.x;

    // ---- sampling location via Horner (redundant per thread, cheap) ----
    const float* rp = ref_polys + (size_t)(b * Q_ + qi) * 8;
    const float t = (float)s * (1.0f / 15.0f);
    const float px = ((rp[0] * t + rp[1]) * t + rp[2]) * t + rp[3];
    const float py = ((rp[4] * t + rp[5]) * t + rp[6]) * t + rp[7];
    const float spx = 2.0f * px - 1.0f;
    const float spy = 2.0f * py - 1.0f;

    // grid_sample align_corners=False, zeros padding, W=H=100
    const float x = (spx + 1.0f) * 50.0f - 0.5f;
    const float y = (spy + 1.0f) * 50.0f - 0.5f;
    const float x0f = floorf(x), y0f = floorf(y);
    const int   x0 = (int)x0f,  y0 = (int)y0f;
    const int   x1 = x0 + 1,    y1 = y0 + 1;
    const float wx1 = x - x0f, wx0 = 1.0f - wx1;
    const float wy1 = y - y0f, wy0 = 1.0f - wy1;
    const bool vx0 = (x0 >= 0) & (x0 < 100);
    const bool vx1 = (x1 >= 0) & (x1 < 100);
    const bool vy0 = (y0 >= 0) & (y0 < 100);
    const bool vy1 = (y1 >= 0) & (y1 < 100);
    const int cx0 = min(max(x0, 0), 99), cx1 = min(max(x1, 0), 99);
    const int cy0 = min(max(y0, 0), 99), cy1 = min(max(y1, 0), 99);
    const float w00 = (vx0 && vy0) ? wx0 * wy0 : 0.0f;
    const float w10 = (vx1 && vy0) ? wx1 * wy0 : 0.0f;
    const float w01 = (vx0 && vy1) ? wx0 * wy1 : 0.0f;
    const float w11 = (vx1 && vy1) ? wx1 * wy1 : 0.0f;

    const float* mb  = memory + (size_t)b * 13125 * 256;
    const float* r00 = mb + (size_t)(cy0 * 100 + cx0) * 256;
    const float* r10 = mb + (size_t)(cy0 * 100 + cx1) * 256;
    const float* r01 = mb + (size_t)(cy1 * 100 + cx0) * 256;
    const float* r11 = mb + (size_t)(cy1 * 100 + cx1) * 256;

    __shared__ float gs[HID_];
    __shared__ float h1s[HID_];

    const int c = tid;   // channel
    float g = w00 * r00[c] + w10 * r10[c] + w01 * r01[c] + w11 * r11[c];
    gs[c] = g;
    __syncthreads();

    // ---- MLP layer 1: thread j computes h1[j] ----
    float acc = b1[tid];
    const float* w1c = w1 + tid;          // column j, stride 256 (coalesced over tid)
    #pragma unroll 8
    for (int k = 0; k < HID_; ++k) {
        acc += gs[k] * w1c[(size_t)k * HID_];
    }
    h1s[tid] = tanhf(acc);
    __syncthreads();

    // ---- MLP layer 2: 4 outputs, wave-0 butterfly reduce ----
    if (tid < 64) {
        float p0 = 0.f, p1 = 0.f, p2 = 0.f, p3 = 0.f;
        #pragma unroll
        for (int j = tid; j < HID_; j += 64) {
            const float h = h1s[j];
            const float* w2r = w2 + j * 4;
            p0 += h * w2r[0];
            p1 += h * w2r[1];
            p2 += h * w2r[2];
            p3 += h * w2r[3];
        }
        #pragma unroll
        for (int off = 32; off; off >>= 1) {
            p0 += __shfl_down(p0, off);
            p1 += __shfl_down(p1, off);
            p2 += __shfl_down(p2, off);
            p3 += __shfl_down(p3, off);
        }
        if (tid == 0) {
            float* o = off_table + ((size_t)bq * 16 + s) * 4;
            o[0] = SSCALE * tanhf(p0 + b2[0]);
            o[1] = SSCALE * tanhf(p1 + b2[1]);
            o[2] = SSCALE * tanhf(p2 + b2[2]);
            o[3] = SSCALE * tanhf(p3 + b2[3]);
        }
    }
}

// One thread per output element. gid = (b*Q+q)*64 + s*4 + np*2 + c
__global__ __launch_bounds__(256) void out_kernel(
    const float* __restrict__ ref_polys,   // [B,Q,8]
    const int*   __restrict__ ref_levels,  // [B,Q]
    const float* __restrict__ off_table,   // [B*3,16,4]
    float* __restrict__ out)               // [B*Q*64]
{
    const int gid  = blockIdx.x * 256 + threadIdx.x;   // 0 .. 307199
    const int lane = gid & 63;
    const int w    = gid >> 6;       // b*Q + q
    const int b    = w / Q_;
    const int s    = lane >> 2;
    const int npc  = lane & 3;       // np*2 + c
    const int c    = lane & 1;

    const float* rp = ref_polys + (size_t)w * 8 + c * 4;
    const float t  = (float)s * (1.0f / 15.0f);
    const float sp = 2.0f * (((rp[0] * t + rp[1]) * t + rp[2]) * t + rp[3]) - 1.0f;

    const int lvl = ref_levels[w];
    const float off = off_table[(((size_t)b * 3 + lvl) * 16 + s) * 4 + npc];
    out[gid] = off + sp;
}

extern "C" void kernel_launch(void* const* d_in, const int* in_sizes, int n_in,
                              void* d_out, int out_size, void* d_ws, size_t ws_size,
                              hipStream_t stream) {
    const float* ref_polys  = (const float*)d_in[0];
    const float* memory     = (const float*)d_in[1];
    const float* w1         = (const float*)d_in[2];
    const float* b1         = (const float*)d_in[3];
    const float* w2         = (const float*)d_in[4];
    const float* b2         = (const float*)d_in[5];
    const int*   ref_levels = (const int*)d_in[6];
    float* out = (float*)d_out;

    float* off_table = (float*)d_ws;   // B*3*16*4 = 3072 floats = 12 KB

    // Stage 1: 768 sample points -> off_table
    sample_mlp_kernel<<<dim3(B_ * 3 * S_), dim3(256), 0, stream>>>(
        ref_polys, memory, w1, b1, w2, b2, off_table);

    // Stage 2: full output, 307200 elements = 1200 blocks * 256
    const int total = B_ * Q_ * S_ * 2 * 2;   // 307200
    out_kernel<<<dim3(total / 256), dim3(256), 0, stream>>>(
        ref_polys, ref_levels, off_table, out);
}